// Round 12
// baseline (516.062 us; speedup 1.0000x reference)
//
#include <hip/hip_runtime.h>
#include <hip/hip_bf16.h>
#include <hip/hip_fp8.h>

#define TT 64   // timesteps
#define LL 64   // layers
#define BB 128  // batch
#define HH 64   // hidden
#define GG 4    // layers per WG (intra-WG staggered)
#define NG 16   // WGs per chain (LL/GG)
#define SL 8    // batch slices
#define RR 16   // rows per slice
#define SB (TT + GG - 1)   // 67 superbeats

typedef short v8s __attribute__((ext_vector_type(8)));   // 8 bf16 (MFMA A/B frag)
typedef float v4f __attribute__((ext_vector_type(4)));   // MFMA C/D frag

// ws layout (bytes):
//   prog  : int[SL][NG] + red[2] @ 300       @ 0    (16 KB reserved)
//   hglob : ull[16slot][NG][SL][RR b][16 w]  @ 16K  (4 MB) tagged fp8 words
//           low 32 = 4 x fp8-e4m3 (u = 4w..4w+3), high 32 = tag t
//   htop  : float[TT][HH][BB]                @ +4MB (2 MB)
//
// R11 structure unchanged. ONE variable changed: all cross-WG loads/stores
// are inline-asm global ops with sc0 sc1 (L1+L2 bypass -> IC-coherent),
// batched so each poll iteration = 4 loads + ONE s_waitcnt vmcnt(0) = 1 RTT.
// No atomic builtins on the critical path (suspected per-access overhead).

__device__ __forceinline__ float sigm(float z)   {
    return __builtin_amdgcn_rcpf(1.f + __expf(-z));
}
__device__ __forceinline__ float tanh_f(float z) {
    return fmaf(-2.f, __builtin_amdgcn_rcpf(1.f + __expf(2.f * z)), 1.f);
}

// 4 tagged-word loads in flight, one waitcnt. Offsets: +0, +8, +64, +72 bytes.
__device__ __forceinline__ void poll4(const unsigned long long* base,
                                      unsigned long long& v0, unsigned long long& v1,
                                      unsigned long long& v2, unsigned long long& v3) {
    asm volatile(
        "global_load_dwordx2 %0, %4, off sc0 sc1\n\t"
        "global_load_dwordx2 %1, %4, off offset:8 sc0 sc1\n\t"
        "global_load_dwordx2 %2, %4, off offset:64 sc0 sc1\n\t"
        "global_load_dwordx2 %3, %4, off offset:72 sc0 sc1\n\t"
        "s_waitcnt vmcnt(0)"
        : "=v"(v0), "=v"(v1), "=v"(v2), "=v"(v3)
        : "v"(base)
        : "memory");
}
__device__ __forceinline__ void gstore64(unsigned long long* p, unsigned long long v) {
    asm volatile("global_store_dwordx2 %0, %1, off sc0 sc1"
                 :: "v"(p), "v"(v) : "memory");
}
__device__ __forceinline__ int fload(const int* p) {
    int v;
    asm volatile("global_load_dword %0, %1, off sc0 sc1\n\ts_waitcnt vmcnt(0)"
                 : "=v"(v) : "v"(p) : "memory");
    return v;
}
__device__ __forceinline__ void fstore(int* p, int v) {
    asm volatile("global_store_dword %0, %1, off sc0 sc1"
                 :: "v"(p), "v"(v) : "memory");
}
__device__ __forceinline__ unsigned short f2bf(float f) {
    unsigned u = __float_as_uint(f);
    return (unsigned short)((u + 0x8000u) >> 16);
}

__global__ __launch_bounds__(512, 2) void lstm_pipeline(
    const float* __restrict__ x,    // [B][T]
    const float* __restrict__ W0,   // [65][256]
    const float* __restrict__ b0,   // [256]
    const float* __restrict__ Wl,   // [63][128][256]
    const float* __restrict__ bl,   // [63][256]
    int* __restrict__ prog,
    unsigned long long* __restrict__ hglob,   // [16][NG][SL][RR][16]
    float* __restrict__ htop)
{
    const int g   = blockIdx.x >> 3;
    const int s   = blockIdx.x & 7;  // batch slice: rows s*16 .. +15
    const int tid = threadIdx.x;
    const int wv  = tid >> 6;
    const int k   = wv >> 1;         // layer within WG (0..3), stagger t = sb-k
    const int nh  = wv & 1;          // n-half: units nh*32 .. +31
    const int ln  = tid & 63;
    const int lr  = ln & 15;
    const int qd  = ln >> 4;
    const int l   = GG * g + k;      // global layer

    __shared__ unsigned short hL[GG][2][RR * 72];  // per-layer h dbuf
    __shared__ float xbuf[RR * 65];                // g==0 input staging

    if (blockIdx.x == 0 && tid < 2) fstore(&prog[300 + tid], 0);  // loss acc+cnt

    for (int i = tid; i < GG * 2 * RR * 72; i += 512)
        ((unsigned short*)hL)[i] = 0;
    if (g == 0) {
        for (int i = tid; i < RR * 64; i += 512)
            xbuf[(i >> 6) * 65 + (i & 63)] =
                x[(size_t)(s * RR + (i >> 6)) * TT + (i & 63)];
    }

    // ---- B-frag gather (one-time): f = tn*4+kf, tn = ut*4+ga ----
    // B[kk][gcol]: kk = kf*32 + qd*8 + j ; gcol = ga*64 + nh*32 + ut*16 + lr.
    v8s bfr[32];
#pragma unroll
    for (int f = 0; f < 32; ++f) {
        const int kf = f & 3, tn = f >> 2;
        const int ga = tn & 3, ut = tn >> 2;
        const int gc = ga * 64 + nh * 32 + ut * 16 + lr;
        v8s tmp;
#pragma unroll
        for (int j = 0; j < 8; ++j) {
            const int kk = kf * 32 + qd * 8 + j;
            float v;
            if (l > 0)        v = Wl[((size_t)(l - 1) * 128 + kk) * 256 + gc];
            else if (kk == 0) v = W0[gc];
            else if (kk < 64) v = 0.f;
            else              v = W0[(size_t)(kk - 63) * 256 + gc];
            tmp[j] = (short)f2bf(v);
        }
        bfr[f] = tmp;
    }

    const float* bs = l ? (bl + (l - 1) * 256) : b0;
    float bias[8];                   // [ut][ga]
#pragma unroll
    for (int i = 0; i < 8; ++i) {
        const int ut = i >> 2, ga = i & 3;
        bias[i] = bs[ga * 64 + nh * 32 + ut * 16 + lr];
    }

    float cst[8];                    // c-state: [ut][r]
#pragma unroll
    for (int i = 0; i < 8; ++i) cst[i] = 0.f;

    __syncthreads();

    for (int sb = 0; sb < SB; ++sb) {
        const int t = sb - k;
        const bool active = (t >= 0) && (t < TT);
        const int rd = (sb - 1) & 1, wr = sb & 1;

        if (active) {
            const int row = lr * 72;
            // own h(t-1) from this layer's dbuf (written at sb-1)
            v8s a2 = *(const v8s*)&hL[k][rd][row + qd * 8];
            v8s a3 = *(const v8s*)&hL[k][rd][row + 32 + qd * 8];
            v8s a0, a1;
            if (k > 0) {             // below = layer k-1's h(t), written at sb-1
                a0 = *(const v8s*)&hL[k - 1][rd][row + qd * 8];
                a1 = *(const v8s*)&hL[k - 1][rd][row + 32 + qd * 8];
            } else if (g > 0) {      // below = WG g-1's L3 tagged fp8 words
                const unsigned long long* rp =
                    hglob + ((((size_t)(t & 15) * NG + (g - 1)) * SL + s) * RR + lr) * 16
                          + qd * 2;
                unsigned int bw0, bw1, bw2, bw3;
                for (;;) {           // 4 loads + ONE waitcnt per iteration
                    unsigned long long v0, v1, v2, v3;
                    poll4(rp, v0, v1, v2, v3);
                    unsigned int ok =
                        (unsigned int)((unsigned int)(v0 >> 32) == (unsigned int)t) &
                        (unsigned int)((unsigned int)(v1 >> 32) == (unsigned int)t) &
                        (unsigned int)((unsigned int)(v2 >> 32) == (unsigned int)t) &
                        (unsigned int)((unsigned int)(v3 >> 32) == (unsigned int)t);
                    if (ok) {
                        bw0 = (unsigned int)v0; bw1 = (unsigned int)v1;
                        bw2 = (unsigned int)v2; bw3 = (unsigned int)v3;
                        break;
                    }
                }
                if (nh == 0 && ln == 0) fstore(&prog[s * NG + g], t + 1);  // ack
                unsigned int ws4[4] = {bw0, bw1, bw2, bw3};
#pragma unroll
                for (int wi = 0; wi < 2; ++wi)
#pragma unroll
                    for (int bi = 0; bi < 4; ++bi) {
                        __hip_fp8_e4m3 f8;
                        f8.__x = (ws4[wi] >> (8 * bi)) & 0xff;
                        a0[wi * 4 + bi] = (short)f2bf((float)f8);
                        f8.__x = (ws4[2 + wi] >> (8 * bi)) & 0xff;
                        a1[wi * 4 + bi] = (short)f2bf((float)f8);
                    }
            } else {                 // global layer 0: below = x_t
                a0 = (v8s){0, 0, 0, 0, 0, 0, 0, 0};
                a1 = (v8s){0, 0, 0, 0, 0, 0, 0, 0};
                if (qd == 0) a0[0] = (short)f2bf(xbuf[lr * 65 + t]);
            }

            v4f acc[8];
#pragma unroll
            for (int i = 0; i < 8; ++i) acc[i] = (v4f){0.f, 0.f, 0.f, 0.f};
#pragma unroll
            for (int tn = 0; tn < 8; ++tn) {
                v4f c = acc[tn];
                c = __builtin_amdgcn_mfma_f32_16x16x32_bf16(a2, bfr[tn * 4 + 2], c, 0, 0, 0);
                c = __builtin_amdgcn_mfma_f32_16x16x32_bf16(a3, bfr[tn * 4 + 3], c, 0, 0, 0);
                c = __builtin_amdgcn_mfma_f32_16x16x32_bf16(a0, bfr[tn * 4 + 0], c, 0, 0, 0);
                c = __builtin_amdgcn_mfma_f32_16x16x32_bf16(a1, bfr[tn * 4 + 1], c, 0, 0, 0);
                acc[tn] = c;
            }

            // slot-reuse gate before k==3 tagged stores (rarely binding)
            if (k == 3 && g < NG - 1 && t >= 14)
                while (fload(&prog[s * NG + (g + 1)]) < t - 14) {}

            unsigned long long* dst =
                hglob + ((((size_t)(t & 15) * NG + g) * SL + s) * RR) * 16;
#pragma unroll
            for (int ut = 0; ut < 2; ++ut) {
                const int u = nh * 32 + ut * 16 + lr;
#pragma unroll
                for (int r = 0; r < 4; ++r) {
                    float zi = acc[ut * 4 + 0][r] + bias[ut * 4 + 0];
                    float zj = acc[ut * 4 + 1][r] + bias[ut * 4 + 1];
                    float zf = acc[ut * 4 + 2][r] + bias[ut * 4 + 2];
                    float zo = acc[ut * 4 + 3][r] + bias[ut * 4 + 3];
                    float c2 = cst[ut * 4 + r] * sigm(zf) + sigm(zi) * tanh_f(zj);
                    cst[ut * 4 + r] = c2;
                    float h2 = tanh_f(c2) * sigm(zo);
                    const int b = qd * 4 + r;
                    hL[k][wr][b * 72 + u] = f2bf(h2);
                    if (k == 3) {
                        if (g < NG - 1) {
                            __hip_fp8_e4m3 f8(h2);
                            unsigned int pk = ((unsigned int)f8.__x) << (8 * (lr & 3));
                            pk |= __shfl_xor(pk, 1);
                            pk |= __shfl_xor(pk, 2);
                            if ((lr & 3) == 0)
                                gstore64(dst + (size_t)b * 16 + nh * 8 + ut * 4 + (lr >> 2),
                                         (unsigned long long)pk |
                                         ((unsigned long long)(unsigned int)t << 32));
                        } else {
                            htop[((size_t)t * HH + u) * BB + s * RR + b] = h2;
                        }
                    }
                }
            }
        }
        __syncthreads();   // dbuf[wr] visible; all reads of dbuf[rd] done
    }
}

__global__ __launch_bounds__(128, 1) void epilogue(
    const float* __restrict__ htop, const float* __restrict__ Wd,
    const float* __restrict__ bd, const float* __restrict__ labels,
    float* __restrict__ out, int* __restrict__ prog)
{
    int t = blockIdx.x, b = threadIdx.x;  // 64 blocks x 128 threads
    float s = 0.f;
#pragma unroll 4
    for (int h = 0; h < HH; ++h)
        s = fmaf(htop[(size_t)t * HH * BB + h * BB + b], Wd[t * HH + h], s);
    s += bd[t];
    s = fmaxf(s, 0.f);
    out[b * TT + t] = s;                  // pred [B][T][1]
    float d = labels[b * TT + t] - s;
    float e = d * d;
#pragma unroll
    for (int off = 32; off > 0; off >>= 1) e += __shfl_down(e, off, 64);
    __shared__ float ws2[2];
    if ((b & 63) == 0) ws2[b >> 6] = e;
    __syncthreads();
    if (b == 0) {
        float* loss = (float*)&prog[300];
        atomicAdd(loss, ws2[0] + ws2[1]);             // device-scope
        __builtin_amdgcn_s_waitcnt(0);
        int done = __hip_atomic_fetch_add(&prog[301], 1, __ATOMIC_ACQ_REL,
                                          __HIP_MEMORY_SCOPE_AGENT);
        if (done == 63) {
            float tot = __hip_atomic_load(loss, __ATOMIC_RELAXED,
                                          __HIP_MEMORY_SCOPE_AGENT);
            out[BB * TT] = tot * (1.f / (BB * TT));
        }
    }
}

extern "C" void kernel_launch(void* const* d_in, const int* in_sizes, int n_in,
                              void* d_out, int out_size, void* d_ws, size_t ws_size,
                              hipStream_t stream) {
    const float* x      = (const float*)d_in[0];
    const float* labels = (const float*)d_in[1];
    const float* W0     = (const float*)d_in[2];
    const float* b0     = (const float*)d_in[3];
    const float* Wl     = (const float*)d_in[4];
    const float* bl     = (const float*)d_in[5];
    const float* Wd     = (const float*)d_in[6];
    const float* bd     = (const float*)d_in[7];
    float* out = (float*)d_out;

    char* base = (char*)d_ws;
    int*                prog  = (int*)base;
    unsigned long long* hglob = (unsigned long long*)(base + 16384);
    float*              htop  = (float*)(base + 16384 + 4194304);

    lstm_pipeline<<<NG * SL, 512, 0, stream>>>(x, W0, b0, Wl, bl, prog, hglob, htop);
    epilogue<<<64, 128, 0, stream>>>(htop, Wd, bd, labels, out, prog);
}

// Round 13
// 487.781 us; speedup vs baseline: 1.0580x; 1.0580x over previous
//
#include <hip/hip_runtime.h>
#include <hip/hip_bf16.h>
#include <hip/hip_fp8.h>

#define TT 64   // timesteps
#define LL 64   // layers
#define BB 128  // batch
#define HH 64   // hidden
#define GG 4    // layers per WG (intra-WG staggered)
#define NG 16   // WGs per chain (LL/GG)
#define SL 8    // batch slices
#define RR 16   // rows per slice
#define SB (TT + GG - 1)   // 67 superbeats

typedef short v8s __attribute__((ext_vector_type(8)));   // 8 bf16 (MFMA A/B frag)
typedef float v4f __attribute__((ext_vector_type(4)));   // MFMA C/D frag

// ws layout (bytes):
//   prog   : int[SL][NG] + red[2] @ 300      @ 0     (16 KB reserved)
//   hglobI : ull[16][NG][SL][RR][16]         @ 16K   (4 MB) sc1/IC insurance copy
//   hglobF : ull[16][NG][SL][RR][16]         @ +4MB  (4 MB) plain/L2 fastpath copy
//   htop   : float[TT][HH][BB]               @ +8MB  (2 MB)
//
// R11 structure. P-cuts this round: (1) light barrier (lgkmcnt-only drain;
// global stores drain in background), (2) slot-gate checked every 8th beat
// (threshold t-7; window 16), (3) dual-path tagged words: plain store ->
// local L2 (fast, valid when consumer shares the XCD - empirically blockIdx%8
// round-robin puts chain s on XCD s) + sc0 sc1 store -> IC (always correct).
// Consumer polls BOTH lines each iteration (8 loads, one waitcnt), accepts
// whichever set carries tag==t. Correct under any placement.

__device__ __forceinline__ float sigm(float z)   {
    return __builtin_amdgcn_rcpf(1.f + __expf(-z));
}
__device__ __forceinline__ float tanh_f(float z) {
    return fmaf(-2.f, __builtin_amdgcn_rcpf(1.f + __expf(2.f * z)), 1.f);
}

// 8 tagged-word loads in flight (4 fastpath L2, 4 insurance IC), one waitcnt.
__device__ __forceinline__ void poll8(const unsigned long long* fast,
                                      const unsigned long long* ins,
                                      unsigned long long* f, unsigned long long* i) {
    asm volatile(
        "global_load_dwordx2 %0, %8, off sc0\n\t"
        "global_load_dwordx2 %1, %8, off offset:8 sc0\n\t"
        "global_load_dwordx2 %2, %8, off offset:64 sc0\n\t"
        "global_load_dwordx2 %3, %8, off offset:72 sc0\n\t"
        "global_load_dwordx2 %4, %9, off sc0 sc1\n\t"
        "global_load_dwordx2 %5, %9, off offset:8 sc0 sc1\n\t"
        "global_load_dwordx2 %6, %9, off offset:64 sc0 sc1\n\t"
        "global_load_dwordx2 %7, %9, off offset:72 sc0 sc1\n\t"
        "s_waitcnt vmcnt(0)"
        : "=v"(f[0]), "=v"(f[1]), "=v"(f[2]), "=v"(f[3]),
          "=v"(i[0]), "=v"(i[1]), "=v"(i[2]), "=v"(i[3])
        : "v"(fast), "v"(ins)
        : "memory");
}
// dual store: plain -> local L2 (fastpath), sc0 sc1 -> IC (insurance)
__device__ __forceinline__ void gstore64_dual(unsigned long long* pf,
                                              unsigned long long* pi,
                                              unsigned long long v) {
    asm volatile(
        "global_store_dwordx2 %0, %2, off\n\t"
        "global_store_dwordx2 %1, %2, off sc0 sc1"
        :: "v"(pf), "v"(pi), "v"(v) : "memory");
}
__device__ __forceinline__ int fload(const int* p) {
    int v;
    asm volatile("global_load_dword %0, %1, off sc0 sc1\n\ts_waitcnt vmcnt(0)"
                 : "=v"(v) : "v"(p) : "memory");
    return v;
}
__device__ __forceinline__ void fstore(int* p, int v) {
    asm volatile("global_store_dword %0, %1, off sc0 sc1"
                 :: "v"(p), "v"(v) : "memory");
}
// light barrier: drain LDS only; global stores keep draining in background
__device__ __forceinline__ void barrier_lds() {
    asm volatile("s_waitcnt lgkmcnt(0)\n\ts_barrier" ::: "memory");
}
__device__ __forceinline__ unsigned short f2bf(float f) {
    unsigned u = __float_as_uint(f);
    return (unsigned short)((u + 0x8000u) >> 16);
}

__global__ __launch_bounds__(512, 2) void lstm_pipeline(
    const float* __restrict__ x,    // [B][T]
    const float* __restrict__ W0,   // [65][256]
    const float* __restrict__ b0,   // [256]
    const float* __restrict__ Wl,   // [63][128][256]
    const float* __restrict__ bl,   // [63][256]
    int* __restrict__ prog,
    unsigned long long* __restrict__ hglobI,  // IC insurance
    unsigned long long* __restrict__ hglobF,  // L2 fastpath
    float* __restrict__ htop)
{
    const int g   = blockIdx.x >> 3;
    const int s   = blockIdx.x & 7;  // batch slice: rows s*16 .. +15
    const int tid = threadIdx.x;
    const int wv  = tid >> 6;
    const int k   = wv >> 1;         // layer within WG (0..3), stagger t = sb-k
    const int nh  = wv & 1;          // n-half: units nh*32 .. +31
    const int ln  = tid & 63;
    const int lr  = ln & 15;
    const int qd  = ln >> 4;
    const int l   = GG * g + k;      // global layer

    __shared__ unsigned short hL[GG][2][RR * 72];  // per-layer h dbuf
    __shared__ float xbuf[RR * 65];                // g==0 input staging

    if (blockIdx.x == 0 && tid < 2) fstore(&prog[300 + tid], 0);  // loss acc+cnt

    for (int i = tid; i < GG * 2 * RR * 72; i += 512)
        ((unsigned short*)hL)[i] = 0;
    if (g == 0) {
        for (int i = tid; i < RR * 64; i += 512)
            xbuf[(i >> 6) * 65 + (i & 63)] =
                x[(size_t)(s * RR + (i >> 6)) * TT + (i & 63)];
    }

    // ---- B-frag gather (one-time): f = tn*4+kf, tn = ut*4+ga ----
    v8s bfr[32];
#pragma unroll
    for (int f = 0; f < 32; ++f) {
        const int kf = f & 3, tn = f >> 2;
        const int ga = tn & 3, ut = tn >> 2;
        const int gc = ga * 64 + nh * 32 + ut * 16 + lr;
        v8s tmp;
#pragma unroll
        for (int j = 0; j < 8; ++j) {
            const int kk = kf * 32 + qd * 8 + j;
            float v;
            if (l > 0)        v = Wl[((size_t)(l - 1) * 128 + kk) * 256 + gc];
            else if (kk == 0) v = W0[gc];
            else if (kk < 64) v = 0.f;
            else              v = W0[(size_t)(kk - 63) * 256 + gc];
            tmp[j] = (short)f2bf(v);
        }
        bfr[f] = tmp;
    }

    const float* bs = l ? (bl + (l - 1) * 256) : b0;
    float bias[8];                   // [ut][ga]
#pragma unroll
    for (int i = 0; i < 8; ++i) {
        const int ut = i >> 2, ga = i & 3;
        bias[i] = bs[ga * 64 + nh * 32 + ut * 16 + lr];
    }

    float cst[8];                    // c-state: [ut][r]
#pragma unroll
    for (int i = 0; i < 8; ++i) cst[i] = 0.f;

    __syncthreads();   // full barrier once (prologue)

    for (int sb = 0; sb < SB; ++sb) {
        const int t = sb - k;
        const bool active = (t >= 0) && (t < TT);
        const int rd = (sb - 1) & 1, wr = sb & 1;

        if (active) {
            const int row = lr * 72;
            v8s a2 = *(const v8s*)&hL[k][rd][row + qd * 8];   // own h(t-1)
            v8s a3 = *(const v8s*)&hL[k][rd][row + 32 + qd * 8];
            v8s a0, a1;
            if (k > 0) {             // below = layer k-1's h(t), via LDS
                a0 = *(const v8s*)&hL[k - 1][rd][row + qd * 8];
                a1 = *(const v8s*)&hL[k - 1][rd][row + 32 + qd * 8];
            } else if (g > 0) {      // below = WG g-1's L3, dual-path tagged words
                const size_t off =
                    ((((size_t)(t & 15) * NG + (g - 1)) * SL + s) * RR + lr) * 16 + qd * 2;
                unsigned int bw0, bw1, bw2, bw3;
                for (;;) {
                    unsigned long long f4[4], i4[4];
                    poll8(hglobF + off, hglobI + off, f4, i4);
                    unsigned int okF = 1, okI = 1;
#pragma unroll
                    for (int q2 = 0; q2 < 4; ++q2) {
                        okF &= (unsigned int)((unsigned int)(f4[q2] >> 32) == (unsigned int)t);
                        okI &= (unsigned int)((unsigned int)(i4[q2] >> 32) == (unsigned int)t);
                    }
                    if (okF | okI) {
                        const unsigned long long* pick = okF ? f4 : i4;
                        bw0 = (unsigned int)pick[0]; bw1 = (unsigned int)pick[1];
                        bw2 = (unsigned int)pick[2]; bw3 = (unsigned int)pick[3];
                        break;
                    }
                }
                if (nh == 0 && ln == 0) fstore(&prog[s * NG + g], t + 1);  // ack
                unsigned int ws4[4] = {bw0, bw1, bw2, bw3};
#pragma unroll
                for (int wi = 0; wi < 2; ++wi)
#pragma unroll
                    for (int bi = 0; bi < 4; ++bi) {
                        __hip_fp8_e4m3 f8;
                        f8.__x = (ws4[wi] >> (8 * bi)) & 0xff;
                        a0[wi * 4 + bi] = (short)f2bf((float)f8);
                        f8.__x = (ws4[2 + wi] >> (8 * bi)) & 0xff;
                        a1[wi * 4 + bi] = (short)f2bf((float)f8);
                    }
            } else {                 // global layer 0: below = x_t
                a0 = (v8s){0, 0, 0, 0, 0, 0, 0, 0};
                a1 = (v8s){0, 0, 0, 0, 0, 0, 0, 0};
                if (qd == 0) a0[0] = (short)f2bf(xbuf[lr * 65 + t]);
            }

            v4f acc[8];
#pragma unroll
            for (int i = 0; i < 8; ++i) acc[i] = (v4f){0.f, 0.f, 0.f, 0.f};
#pragma unroll
            for (int tn = 0; tn < 8; ++tn) {
                v4f c = acc[tn];
                c = __builtin_amdgcn_mfma_f32_16x16x32_bf16(a2, bfr[tn * 4 + 2], c, 0, 0, 0);
                c = __builtin_amdgcn_mfma_f32_16x16x32_bf16(a3, bfr[tn * 4 + 3], c, 0, 0, 0);
                c = __builtin_amdgcn_mfma_f32_16x16x32_bf16(a0, bfr[tn * 4 + 0], c, 0, 0, 0);
                c = __builtin_amdgcn_mfma_f32_16x16x32_bf16(a1, bfr[tn * 4 + 1], c, 0, 0, 0);
                acc[tn] = c;
            }

            // slot-reuse gate: every 8th beat, amortized (window 16, margin 8)
            if (k == 3 && g < NG - 1 && t >= 16 && (t & 7) == 0)
                while (fload(&prog[s * NG + (g + 1)]) < t - 7) {}

            const size_t dbase = (((size_t)(t & 15) * NG + g) * SL + s) * RR * 16;
#pragma unroll
            for (int ut = 0; ut < 2; ++ut) {
                const int u = nh * 32 + ut * 16 + lr;
#pragma unroll
                for (int r = 0; r < 4; ++r) {
                    float zi = acc[ut * 4 + 0][r] + bias[ut * 4 + 0];
                    float zj = acc[ut * 4 + 1][r] + bias[ut * 4 + 1];
                    float zf = acc[ut * 4 + 2][r] + bias[ut * 4 + 2];
                    float zo = acc[ut * 4 + 3][r] + bias[ut * 4 + 3];
                    float c2 = cst[ut * 4 + r] * sigm(zf) + sigm(zi) * tanh_f(zj);
                    cst[ut * 4 + r] = c2;
                    float h2 = tanh_f(c2) * sigm(zo);
                    const int b = qd * 4 + r;
                    hL[k][wr][b * 72 + u] = f2bf(h2);
                    if (k == 3) {
                        if (g < NG - 1) {
                            __hip_fp8_e4m3 f8(h2);
                            unsigned int pk = ((unsigned int)f8.__x) << (8 * (lr & 3));
                            pk |= __shfl_xor(pk, 1);
                            pk |= __shfl_xor(pk, 2);
                            if ((lr & 3) == 0) {
                                const size_t o = dbase + (size_t)b * 16 + nh * 8 + ut * 4 + (lr >> 2);
                                gstore64_dual(hglobF + o, hglobI + o,
                                              (unsigned long long)pk |
                                              ((unsigned long long)(unsigned int)t << 32));
                            }
                        } else {
                            htop[((size_t)t * HH + u) * BB + s * RR + b] = h2;
                        }
                    }
                }
            }
        }
        barrier_lds();   // LDS drained; global stores drain in background
    }
}

__global__ __launch_bounds__(128, 1) void epilogue(
    const float* __restrict__ htop, const float* __restrict__ Wd,
    const float* __restrict__ bd, const float* __restrict__ labels,
    float* __restrict__ out, int* __restrict__ prog)
{
    int t = blockIdx.x, b = threadIdx.x;  // 64 blocks x 128 threads
    float s = 0.f;
#pragma unroll 4
    for (int h = 0; h < HH; ++h)
        s = fmaf(htop[(size_t)t * HH * BB + h * BB + b], Wd[t * HH + h], s);
    s += bd[t];
    s = fmaxf(s, 0.f);
    out[b * TT + t] = s;                  // pred [B][T][1]
    float d = labels[b * TT + t] - s;
    float e = d * d;
#pragma unroll
    for (int off = 32; off > 0; off >>= 1) e += __shfl_down(e, off, 64);
    __shared__ float ws2[2];
    if ((b & 63) == 0) ws2[b >> 6] = e;
    __syncthreads();
    if (b == 0) {
        float* loss = (float*)&prog[300];
        atomicAdd(loss, ws2[0] + ws2[1]);             // device-scope
        __builtin_amdgcn_s_waitcnt(0);
        int done = __hip_atomic_fetch_add(&prog[301], 1, __ATOMIC_ACQ_REL,
                                          __HIP_MEMORY_SCOPE_AGENT);
        if (done == 63) {
            float tot = __hip_atomic_load(loss, __ATOMIC_RELAXED,
                                          __HIP_MEMORY_SCOPE_AGENT);
            out[BB * TT] = tot * (1.f / (BB * TT));
        }
    }
}

extern "C" void kernel_launch(void* const* d_in, const int* in_sizes, int n_in,
                              void* d_out, int out_size, void* d_ws, size_t ws_size,
                              hipStream_t stream) {
    const float* x      = (const float*)d_in[0];
    const float* labels = (const float*)d_in[1];
    const float* W0     = (const float*)d_in[2];
    const float* b0     = (const float*)d_in[3];
    const float* Wl     = (const float*)d_in[4];
    const float* bl     = (const float*)d_in[5];
    const float* Wd     = (const float*)d_in[6];
    const float* bd     = (const float*)d_in[7];
    float* out = (float*)d_out;

    char* base = (char*)d_ws;
    int*                prog   = (int*)base;
    unsigned long long* hglobI = (unsigned long long*)(base + 16384);
    unsigned long long* hglobF = (unsigned long long*)(base + 16384 + 4194304);
    float*              htop   = (float*)(base + 16384 + 8388608);

    lstm_pipeline<<<NG * SL, 512, 0, stream>>>(x, W0, b0, Wl, bl, prog,
                                               hglobI, hglobF, htop);
    epilogue<<<64, 128, 0, stream>>>(htop, Wd, bd, labels, out, prog);
}